// Round 16
// baseline (4667.545 us; speedup 1.0000x reference)
//
#include <hip/hip_runtime.h>
#include <math.h>

namespace {

constexpr int B = 8, T = 10, C = 32, H = 128, W = 128;
constexpr int HW = H * W;            // 16384
constexpr int CHW = C * HW;          // 524288
constexpr int BHW = B * HW;
constexpr long long NSTATE = (long long)B * CHW;

constexpr float DF = 0.90483741803595952f;  // exp(-0.1)
constexpr float DL = 0.36787944117144233f;  // exp(-1.0)
constexpr float DE = 0.36787944117144233f;  // exp(-1.0)
constexpr float VE = 10.0f;
constexpr float E0 = 3.6787944117144233f;   // DE * (V_E/ALPHA_E), e-fold init

// wgt[co][ci][kh][kw] -> wtr[ci][k][co]   (9216 floats)
__global__ void k_wtr(const float* __restrict__ wgt, float* __restrict__ wtr) {
  int i = blockIdx.x * 256 + threadIdx.x;
  if (i >= C * C * 9) return;
  int ci = i / 288;
  int k = (i / 32) % 9;
  int co = i & 31;
  wtr[i] = wgt[co * 288 + ci * 9 + k];
}

// t=0: y_prev=0 -> conv=0, l=0, u=f. Writes f, e_used(1), out[0], l-plane.
__launch_bounds__(256, 2)
__global__ void k_step0(const float* __restrict__ x, const float* __restrict__ bias,
                        float* __restrict__ f, float* __restrict__ e,
                        float* __restrict__ lpl, float* __restrict__ out) {
  const int tid = threadIdx.x, bid = blockIdx.x;
  const int wg = (bid & 7) * 128 + (bid >> 3);  // XCD swizzle
  const int tw = wg & 7, th = (wg >> 3) & 15, b = wg >> 7;
  const int h0 = th * 8, w0 = tw * 16;
  const int g = tid >> 5, s = tid & 31;
  const int sh = s >> 2, sw = s & 3, cb = 4 * sw;
  const int gh = h0 + sh, gwc = w0 + cb;
  const float4 bc4 = *(const float4*)&bias[4 * g];
  const float bc[4] = {bc4.x, bc4.y, bc4.z, bc4.w};

#pragma unroll
  for (int q = 0; q < 4; ++q) {
    const int c = 4 * g + q;
    const size_t sidx = (size_t)b * CHW + (size_t)c * HW + (size_t)gh * W + gwc;
    const size_t oidx = (((size_t)b * T) * C + c) * (size_t)HW + (size_t)gh * W + gwc;
    float4 x4 = *(const float4*)(x + oidx);
    float xr[4] = {x4.x, x4.y, x4.z, x4.w};
    float fo[4], eo[4], yn[4];
#pragma unroll
    for (int p = 0; p < 4; ++p) {
      float fn = bc[q] + xr[p];                  // DF*0 + conv(0) + bias + x
      float yy = 1.f / (1.f + __expf(E0 - fn));  // u = fn (l=0)
      fo[p] = fn;
      eo[p] = DE * E0 + VE * yy;                 // e_used(1)
      yn[p] = yy;
    }
    *(float4*)(f + sidx) = make_float4(fo[0], fo[1], fo[2], fo[3]);
    *(float4*)(e + sidx) = make_float4(eo[0], eo[1], eo[2], eo[3]);
    *(float4*)(out + oidx) = make_float4(yn[0], yn[1], yn[2], yn[3]);
  }
  if (tid < 32) {
    const size_t pidx = (size_t)b * HW + (size_t)gh * W + gwc;
    *(float4*)(lpl + pidx) = make_float4(0.f, 0.f, 0.f, 0.f);  // l_1 = 0
  }
}

// Steps 1..T-1. EXACT R12 structure (best verified: 58us/step) with one
// register-neutral graft: the channel-sum for the fixed conv is accumulated
// from the staged y chunks (R13-proven correct), deleting the s ping-pong
// planes, the prologue s-stage, and the sred epilogue phase.
// R12 demand sits near the 128 cap (R13/R15 lesson) -> every delta here is
// register-neutral: y offsets narrowed to int (-2), scol/srr/scl (+3).
__launch_bounds__(256, 2)
__global__ void k_step(const float* __restrict__ x, const float* __restrict__ wtr,
                       const float* __restrict__ bias, float* __restrict__ f,
                       float* __restrict__ e, float* __restrict__ lpl,
                       float* __restrict__ out, int t) {
  __shared__ float ysl[8][10][28];   // stride 28: rows 16B-aligned, 2-way banks
  __shared__ float wsl[8][9][32];    // [ci][k][c_out]
  __shared__ float sl[10][21];       // chansum tile (+halo)

  const int tid = threadIdx.x, bid = blockIdx.x;
  const int wg = (bid & 7) * 128 + (bid >> 3);  // XCD swizzle: batch per XCD
  const int tw = wg & 7, th = (wg >> 3) & 15, b = wg >> 7;
  const int h0 = th * 8, w0 = tw * 16;
  const int g = tid >> 5, s = tid & 31;
  const int sh = s >> 2, sw = s & 3, cb = 4 * sw;
  const int gh = h0 + sh, gwc = w0 + cb;

  const float* ybase = out + ((size_t)b * T + (t - 1)) * CHW;

  // l-plane read (channel-uniform)
  float4 l4 = *(const float4*)(lpl + (size_t)b * HW + (size_t)gh * W + gwc);
  float lold[4] = {l4.x, l4.y, l4.z, l4.w};

  // y-prefetch slots (chunk-invariant address parts). 480 float4 per chunk.
  const int i0 = tid;                                  // slot 0: always valid
  const int cil0 = i0 / 60, rr0 = (i0 % 60) / 6, j0 = i0 % 6;
  const int gh0p = h0 - 1 + rr0, ws0p = w0 - 4 + 4 * j0;
  const bool ok0 = (unsigned)gh0p < (unsigned)H && (unsigned)ws0p <= (unsigned)(W - 4);
  const int yoff0 = cil0 * HW + (ok0 ? gh0p * W + ws0p : 0);
  float* const yd0 = &ysl[cil0][rr0][4 * j0];
  const int i1 = tid + 256;                            // slot 1: valid if <480
  const bool use1 = i1 < 480;
  const int cil1 = (i1 / 60) & 7, rr1 = (i1 % 60) / 6, j1 = i1 % 6;
  const int gh1p = h0 - 1 + rr1, ws1p = w0 - 4 + 4 * j1;
  const bool ok1 = use1 && (unsigned)gh1p < (unsigned)H &&
                   (unsigned)ws1p <= (unsigned)(W - 4);
  const int yoff1 = cil1 * HW + (ok1 ? gh1p * W + ws1p : 0);
  float* const yd1 = &ysl[cil1][rr1][4 * j1];

  const float4* const wsrc = (const float4*)wtr;       // 576 float4 per chunk
  float4* const wlds = (float4*)&wsl[0][0][0];

  float4 y0v, y1v, w0v, w1v, w2v;
  auto prefetch = [&](int cc) {
    const float* yb = ybase + cc * (8 * HW);
    y0v = ok0 ? *(const float4*)(yb + yoff0) : make_float4(0.f, 0.f, 0.f, 0.f);
    y1v = ok1 ? *(const float4*)(yb + yoff1) : make_float4(0.f, 0.f, 0.f, 0.f);
    const float4* wb = wsrc + cc * 576;
    w0v = wb[tid];
    w1v = wb[tid + 256];
    w2v = (tid < 64) ? wb[tid + 512] : make_float4(0.f, 0.f, 0.f, 0.f);
  };
  auto commit = [&]() {
    yd0[0] = y0v.x; yd0[1] = y0v.y; yd0[2] = y0v.z; yd0[3] = y0v.w;
    if (use1) { yd1[0] = y1v.x; yd1[1] = y1v.y; yd1[2] = y1v.z; yd1[3] = y1v.w; }
    wlds[tid] = w0v;
    wlds[tid + 256] = w1v;
    if (tid < 64) wlds[tid + 512] = w2v;
  };
  prefetch(0);

  float acc[4][4] = {};
  float scol = 0.f;                     // chansum accumulator (tid<180)
  const int srr = tid / 18, scl = tid % 18;

  auto conv_chunk = [&]() {
#pragma unroll
    for (int cil = 0; cil < 8; ++cil) {
#pragma unroll
      for (int kh = 0; kh < 3; ++kh) {
        const float* rowp = &ysl[cil][sh + kh][0];
        float2 a2 = *(const float2*)(rowp + cb + 2);   // slots cb+2,cb+3
        float4 m4 = *(const float4*)(rowp + cb + 4);   // slots cb+4..cb+7
        float2 z2 = *(const float2*)(rowp + cb + 8);   // slots cb+8,cb+9
        const float yrow[6] = {a2.y, m4.x, m4.y, m4.z, m4.w, z2.x};
#pragma unroll
        for (int kw = 0; kw < 3; ++kw) {
          float4 wk = *(const float4*)&wsl[cil][3 * kh + kw][4 * g];
          const float wq[4] = {wk.x, wk.y, wk.z, wk.w};
#pragma unroll
          for (int q = 0; q < 4; ++q)
#pragma unroll
            for (int p = 0; p < 4; ++p)
              acc[q][p] = fmaf(wq[q], yrow[p + kw], acc[q][p]);
        }
      }
    }
    // chansum rides the staged chunk: 8 x ds_read_b32 (imm offsets) tid<180
    if (tid < 180) {
      const float* yb = &ysl[0][srr][scl + 3];
#pragma unroll
      for (int ci = 0; ci < 8; ++ci) scol += yb[ci * 280];
    }
  };

#pragma unroll 1
  for (int cc = 0; cc < 3; ++cc) {
    __syncthreads();  // previous chunk's LDS reads complete
    commit();
    __syncthreads();  // LDS visible
    prefetch(cc + 1);  // next chunk's loads fly under these FMAs
    conv_chunk();
  }

  // chunk 3 (peeled): commit, then EARLY f/e loads (prefetch regs just died),
  // then the last FMA block — load latency hides under 1152 FMAs.
  __syncthreads();
  commit();
  __syncthreads();
  float4 fq4[4], eq4[4];
#pragma unroll
  for (int q = 0; q < 4; ++q) {
    const size_t sidx =
        (size_t)b * CHW + (size_t)(4 * g + q) * HW + (size_t)gh * W + gwc;
    fq4[q] = *(const float4*)(f + sidx);
    eq4[q] = *(const float4*)(e + sidx);
  }
  conv_chunk();

  // finalize chansum tile, then l-inc
  __syncthreads();  // all chunk-3 reads done before sl overwrite? (sl separate
                    // array, but need all scol writes ordered before reads)
  if (tid < 180) sl[srr][scl] = scol;
  __syncthreads();
  float lnew[4];
#pragma unroll
  for (int p = 0; p < 4; ++p) {
    const int c0 = cb + p;
    float linc =
        0.5f * (sl[sh][c0] + sl[sh][c0 + 2] + sl[sh + 2][c0] + sl[sh + 2][c0 + 2]) +
        sl[sh][c0 + 1] + sl[sh + 2][c0 + 1] + sl[sh + 1][c0] + sl[sh + 1][c0 + 2];
    lnew[p] = DL * lold[p] + linc;
  }

  // epilogue: f/e update (e-fold), out write
  const float4 bc4 = *(const float4*)&bias[4 * g];
  const float bc[4] = {bc4.x, bc4.y, bc4.z, bc4.w};
#pragma unroll
  for (int q = 0; q < 4; ++q) {
    const int c = 4 * g + q;
    const size_t sidx = (size_t)b * CHW + (size_t)c * HW + (size_t)gh * W + gwc;
    const size_t oidx = (((size_t)b * T + t) * C + c) * (size_t)HW + (size_t)gh * W + gwc;
    float4 x4 = *(const float4*)(x + oidx);
    float fr[4] = {fq4[q].x, fq4[q].y, fq4[q].z, fq4[q].w};
    float er[4] = {eq4[q].x, eq4[q].y, eq4[q].z, eq4[q].w};
    float xr[4] = {x4.x, x4.y, x4.z, x4.w};
    float fo[4], eo[4], yn[4];
#pragma unroll
    for (int p = 0; p < 4; ++p) {
      float fn = DF * fr[p] + acc[q][p] + bc[q] + xr[p];
      float u = fmaf(0.5f * fn, lnew[p], fn);
      float yy = 1.f / (1.f + __expf(er[p] - u));
      fo[p] = fn;
      eo[p] = DE * er[p] + VE * yy;  // e_used(t+1)
      yn[p] = yy;
    }
    *(float4*)(f + sidx) = make_float4(fo[0], fo[1], fo[2], fo[3]);
    *(float4*)(e + sidx) = make_float4(eo[0], eo[1], eo[2], eo[3]);
    *(float4*)(out + oidx) = make_float4(yn[0], yn[1], yn[2], yn[3]);
  }
  if (tid < 32) {  // g==0 threads span the tile: store l-plane
    const size_t pidx = (size_t)b * HW + (size_t)gh * W + gwc;
    *(float4*)(lpl + pidx) = make_float4(lnew[0], lnew[1], lnew[2], lnew[3]);
  }
}

}  // namespace

extern "C" void kernel_launch(void* const* d_in, const int* in_sizes, int n_in,
                              void* d_out, int out_size, void* d_ws, size_t ws_size,
                              hipStream_t stream) {
  (void)in_sizes; (void)n_in; (void)out_size; (void)ws_size;
  const float* x = (const float*)d_in[0];     // (B,T,C,H,W)
  const float* wgt = (const float*)d_in[1];   // (C,C,3,3)
  const float* bias = (const float*)d_in[2];  // (C,)
  float* out = (float*)d_out;                 // (B,T,C,H,W)

  float* ws = (float*)d_ws;
  float* f = ws;                    // NSTATE
  float* e = f + NSTATE;            // NSTATE
  float* lpl = e + NSTATE;          // BHW (l is channel-uniform)
  float* wtr = lpl + BHW;           // 9216

  k_wtr<<<36, 256, 0, stream>>>(wgt, wtr);
  k_step0<<<1024, 256, 0, stream>>>(x, bias, f, e, lpl, out);

  for (int t = 1; t < T; ++t) {
    k_step<<<1024, 256, 0, stream>>>(x, wtr, bias, f, e, lpl, out, t);
  }
}

// Round 17
// 570.886 us; speedup vs baseline: 8.1760x; 8.1760x over previous
//
#include <hip/hip_runtime.h>
#include <math.h>

namespace {

constexpr int B = 8, T = 10, C = 32, H = 128, W = 128;
constexpr int HW = H * W;            // 16384
constexpr int CHW = C * HW;          // 524288
constexpr int BHW = B * HW;
constexpr long long NSTATE = (long long)B * CHW;

constexpr float DF = 0.90483741803595952f;  // exp(-0.1)
constexpr float DL = 0.36787944117144233f;  // exp(-1.0)
constexpr float DE = 0.36787944117144233f;  // exp(-1.0)
constexpr float VE = 10.0f;
constexpr float E0 = 3.6787944117144233f;   // DE * (V_E/ALPHA_E), e-fold init

// wgt[co][ci][kh][kw] -> wtr[ci][k][co]   (9216 floats)
__global__ void k_wtr(const float* __restrict__ wgt, float* __restrict__ wtr) {
  int i = blockIdx.x * 256 + threadIdx.x;
  if (i >= C * C * 9) return;
  int ci = i / 288;
  int k = (i / 32) % 9;
  int co = i & 31;
  wtr[i] = wgt[co * 288 + ci * 9 + k];
}

// t=0: y_prev=0 -> conv=0, l=0, u=f. Writes f, e_used(1), out[0], s, l-plane.
__launch_bounds__(256, 2)
__global__ void k_step0(const float* __restrict__ x, const float* __restrict__ bias,
                        float* __restrict__ f, float* __restrict__ e,
                        float* __restrict__ lpl, float* __restrict__ out,
                        float* __restrict__ s_out) {
  __shared__ float sred[8][32][4];
  const int tid = threadIdx.x, bid = blockIdx.x;
  const int wg = (bid & 7) * 128 + (bid >> 3);  // XCD swizzle: batch per XCD
  const int tw = wg & 7, th = (wg >> 3) & 15, b = wg >> 7;
  const int h0 = th * 8, w0 = tw * 16;
  const int g = tid >> 5, s = tid & 31;
  const int sh = s >> 2, sw = s & 3, cb = 4 * sw;
  const int gh = h0 + sh, gwc = w0 + cb;
  const float4 bc4 = *(const float4*)&bias[4 * g];
  const float bc[4] = {bc4.x, bc4.y, bc4.z, bc4.w};

  float sp[4] = {0.f, 0.f, 0.f, 0.f};
#pragma unroll
  for (int q = 0; q < 4; ++q) {
    const int c = 4 * g + q;
    const size_t sidx = (size_t)b * CHW + (size_t)c * HW + (size_t)gh * W + gwc;
    const size_t oidx = (((size_t)b * T) * C + c) * (size_t)HW + (size_t)gh * W + gwc;
    float4 x4 = *(const float4*)(x + oidx);
    float xr[4] = {x4.x, x4.y, x4.z, x4.w};
    float fo[4], eo[4], yn[4];
#pragma unroll
    for (int p = 0; p < 4; ++p) {
      float fn = bc[q] + xr[p];                  // DF*0 + conv(0) + bias + x
      float yy = 1.f / (1.f + __expf(E0 - fn));  // u = fn (l=0)
      fo[p] = fn;
      eo[p] = DE * E0 + VE * yy;                 // e_used(1)
      yn[p] = yy;
      sp[p] += yy;
    }
    *(float4*)(f + sidx) = make_float4(fo[0], fo[1], fo[2], fo[3]);
    *(float4*)(e + sidx) = make_float4(eo[0], eo[1], eo[2], eo[3]);
    *(float4*)(out + oidx) = make_float4(yn[0], yn[1], yn[2], yn[3]);
  }
  *(float4*)&sred[g][s][0] = make_float4(sp[0], sp[1], sp[2], sp[3]);
  __syncthreads();
  if (tid < 32) {
    float4 a = *(const float4*)&sred[0][tid][0];
#pragma unroll
    for (int gg = 1; gg < 8; ++gg) {
      float4 bq = *(const float4*)&sred[gg][tid][0];
      a.x += bq.x; a.y += bq.y; a.z += bq.z; a.w += bq.w;
    }
    const size_t pidx = (size_t)b * HW + (size_t)gh * W + gwc;
    *(float4*)(s_out + pidx) = a;
    *(float4*)(lpl + pidx) = make_float4(0.f, 0.f, 0.f, 0.f);  // l_1 = 0
  }
}

// Steps 1..T-1. R9-proven structure (register shape ~92-110, no spill):
// 1024 blocks x 256 threads, tile 8x16, all 32 c_out; ci in 4 chunks of 8,
// single LDS buffer + register prefetch (T14). New vs R9:
//  (a) XCD swizzle: batch <-> XCD, y-halo/f/e L2-local.
//  (b) chunk 3 peeled: f/e epilogue loads issued right after its commit
//      (prefetch regs just died), latency hides under the last 1152 FMAs.
__launch_bounds__(256, 2)
__global__ void k_step(const float* __restrict__ x, const float* __restrict__ wtr,
                       const float* __restrict__ bias, const float* __restrict__ s_in,
                       float* __restrict__ s_out, float* __restrict__ f,
                       float* __restrict__ e, float* __restrict__ lpl,
                       float* __restrict__ out, int t) {
  __shared__ float ysl[8][10][28];   // stride 28: rows 16B-aligned, 2-way banks
  __shared__ float wsl[8][9][32];    // [ci][k][c_out]
  __shared__ float sl[10][21];       // channel-sum tile (+halo)
  __shared__ float sred[8][32][4];   // chansum partials

  const int tid = threadIdx.x, bid = blockIdx.x;
  const int wg = (bid & 7) * 128 + (bid >> 3);  // XCD swizzle: batch per XCD
  const int tw = wg & 7, th = (wg >> 3) & 15, b = wg >> 7;
  const int h0 = th * 8, w0 = tw * 16;
  const int g = tid >> 5, s = tid & 31;
  const int sh = s >> 2, sw = s & 3, cb = 4 * sw;
  const int gh = h0 + sh, gwc = w0 + cb;

  const float* ybase = out + ((size_t)b * T + (t - 1)) * CHW;

  // stage channel-sum tile (visible after first barrier)
  for (int i = tid; i < 180; i += 256) {
    int rr = i / 18, cl = i % 18;
    int gh2 = h0 - 1 + rr, gw2 = w0 - 1 + cl;
    float v = 0.f;
    if ((unsigned)gh2 < (unsigned)H && (unsigned)gw2 < (unsigned)W)
      v = s_in[(size_t)b * HW + gh2 * W + gw2];
    sl[rr][cl] = v;
  }

  // l-plane read (channel-uniform); becomes l_new once linc is known
  float4 l4 = *(const float4*)(lpl + (size_t)b * HW + (size_t)gh * W + gwc);
  float lnew[4] = {l4.x, l4.y, l4.z, l4.w};

  // y-prefetch slots (chunk-invariant address parts). 480 float4 per chunk.
  const int i0 = tid;                                  // slot 0: always valid
  const int cil0 = i0 / 60, rr0 = (i0 % 60) / 6, j0 = i0 % 6;
  const int gh0p = h0 - 1 + rr0, ws0p = w0 - 4 + 4 * j0;
  const bool ok0 = (unsigned)gh0p < (unsigned)H && (unsigned)ws0p <= (unsigned)(W - 4);
  const size_t yoff0 = (size_t)cil0 * HW + (size_t)(ok0 ? gh0p * W + ws0p : 0);
  float* const yd0 = &ysl[cil0][rr0][4 * j0];
  const int i1 = tid + 256;                            // slot 1: valid if <480
  const bool use1 = i1 < 480;
  const int cil1 = (i1 / 60) & 7, rr1 = (i1 % 60) / 6, j1 = i1 % 6;
  const int gh1p = h0 - 1 + rr1, ws1p = w0 - 4 + 4 * j1;
  const bool ok1 = use1 && (unsigned)gh1p < (unsigned)H &&
                   (unsigned)ws1p <= (unsigned)(W - 4);
  const size_t yoff1 = (size_t)cil1 * HW + (size_t)(ok1 ? gh1p * W + ws1p : 0);
  float* const yd1 = &ysl[cil1][rr1][4 * j1];

  const float4* const wsrc = (const float4*)wtr;       // 576 float4 per chunk
  float4* const wlds = (float4*)&wsl[0][0][0];

  float4 y0v, y1v, w0v, w1v, w2v;
  auto prefetch = [&](int cc) {
    const float* yb = ybase + (size_t)cc * 8 * HW;
    y0v = ok0 ? *(const float4*)(yb + yoff0) : make_float4(0.f, 0.f, 0.f, 0.f);
    y1v = ok1 ? *(const float4*)(yb + yoff1) : make_float4(0.f, 0.f, 0.f, 0.f);
    const float4* wb = wsrc + cc * 576;
    w0v = wb[tid];
    w1v = wb[tid + 256];
    w2v = (tid < 64) ? wb[tid + 512] : make_float4(0.f, 0.f, 0.f, 0.f);
  };
  auto commit = [&]() {
    yd0[0] = y0v.x; yd0[1] = y0v.y; yd0[2] = y0v.z; yd0[3] = y0v.w;
    if (use1) { yd1[0] = y1v.x; yd1[1] = y1v.y; yd1[2] = y1v.z; yd1[3] = y1v.w; }
    wlds[tid] = w0v;
    wlds[tid + 256] = w1v;
    if (tid < 64) wlds[tid + 512] = w2v;
  };
  prefetch(0);

  float acc[4][4] = {};

  auto conv_chunk = [&]() {
#pragma unroll
    for (int cil = 0; cil < 8; ++cil) {
#pragma unroll
      for (int kh = 0; kh < 3; ++kh) {
        const float* rowp = &ysl[cil][sh + kh][0];
        float2 a2 = *(const float2*)(rowp + cb + 2);   // slots cb+2,cb+3
        float4 m4 = *(const float4*)(rowp + cb + 4);   // slots cb+4..cb+7
        float2 z2 = *(const float2*)(rowp + cb + 8);   // slots cb+8,cb+9
        const float yrow[6] = {a2.y, m4.x, m4.y, m4.z, m4.w, z2.x};
#pragma unroll
        for (int kw = 0; kw < 3; ++kw) {
          float4 wk = *(const float4*)&wsl[cil][3 * kh + kw][4 * g];
          const float wq[4] = {wk.x, wk.y, wk.z, wk.w};
#pragma unroll
          for (int q = 0; q < 4; ++q)
#pragma unroll
            for (int p = 0; p < 4; ++p)
              acc[q][p] = fmaf(wq[q], yrow[p + kw], acc[q][p]);
        }
      }
    }
  };

#pragma unroll 1
  for (int cc = 0; cc < 3; ++cc) {
    __syncthreads();  // previous chunk's LDS reads complete
    commit();
    __syncthreads();  // LDS visible
    prefetch(cc + 1);  // next chunk's loads fly under these FMAs
    if (cc == 0) {
      float linc[4];
#pragma unroll
      for (int p = 0; p < 4; ++p) {
        const int c0 = cb + p;
        linc[p] = 0.5f * (sl[sh][c0] + sl[sh][c0 + 2] + sl[sh + 2][c0] +
                          sl[sh + 2][c0 + 2]) +
                  sl[sh][c0 + 1] + sl[sh + 2][c0 + 1] + sl[sh + 1][c0] +
                  sl[sh + 1][c0 + 2];
      }
#pragma unroll
      for (int p = 0; p < 4; ++p) lnew[p] = DL * lnew[p] + linc[p];
    }
    conv_chunk();
  }

  // chunk 3 (peeled): commit, then EARLY f/e loads (prefetch regs just died),
  // then the last FMA block — load latency hides under 1152 FMAs.
  __syncthreads();
  commit();
  __syncthreads();
  float4 fq4[4], eq4[4];
#pragma unroll
  for (int q = 0; q < 4; ++q) {
    const size_t sidx =
        (size_t)b * CHW + (size_t)(4 * g + q) * HW + (size_t)gh * W + gwc;
    fq4[q] = *(const float4*)(f + sidx);
    eq4[q] = *(const float4*)(e + sidx);
  }
  conv_chunk();

  // epilogue: f/e update (e-fold), out write, chansum partials
  const float4 bc4 = *(const float4*)&bias[4 * g];
  const float bc[4] = {bc4.x, bc4.y, bc4.z, bc4.w};
  float sp[4] = {0.f, 0.f, 0.f, 0.f};
#pragma unroll
  for (int q = 0; q < 4; ++q) {
    const int c = 4 * g + q;
    const size_t sidx = (size_t)b * CHW + (size_t)c * HW + (size_t)gh * W + gwc;
    const size_t oidx = (((size_t)b * T + t) * C + c) * (size_t)HW + (size_t)gh * W + gwc;
    float4 x4 = *(const float4*)(x + oidx);
    float fr[4] = {fq4[q].x, fq4[q].y, fq4[q].z, fq4[q].w};
    float er[4] = {eq4[q].x, eq4[q].y, eq4[q].z, eq4[q].w};
    float xr[4] = {x4.x, x4.y, x4.z, x4.w};
    float fo[4], eo[4], yn[4];
#pragma unroll
    for (int p = 0; p < 4; ++p) {
      float fn = DF * fr[p] + acc[q][p] + bc[q] + xr[p];
      float u = fmaf(0.5f * fn, lnew[p], fn);
      float yy = 1.f / (1.f + __expf(er[p] - u));
      fo[p] = fn;
      eo[p] = DE * er[p] + VE * yy;  // e_used(t+1)
      yn[p] = yy;
      sp[p] += yy;
    }
    *(float4*)(f + sidx) = make_float4(fo[0], fo[1], fo[2], fo[3]);
    *(float4*)(e + sidx) = make_float4(eo[0], eo[1], eo[2], eo[3]);
    *(float4*)(out + oidx) = make_float4(yn[0], yn[1], yn[2], yn[3]);
  }
  *(float4*)&sred[g][s][0] = make_float4(sp[0], sp[1], sp[2], sp[3]);
  __syncthreads();
  if (tid < 32) {  // g==0 threads span the tile
    float4 a = *(const float4*)&sred[0][tid][0];
#pragma unroll
    for (int gg = 1; gg < 8; ++gg) {
      float4 bq = *(const float4*)&sred[gg][tid][0];
      a.x += bq.x; a.y += bq.y; a.z += bq.z; a.w += bq.w;
    }
    const size_t pidx = (size_t)b * HW + (size_t)gh * W + gwc;
    *(float4*)(s_out + pidx) = a;
    *(float4*)(lpl + pidx) = make_float4(lnew[0], lnew[1], lnew[2], lnew[3]);
  }
}

}  // namespace

extern "C" void kernel_launch(void* const* d_in, const int* in_sizes, int n_in,
                              void* d_out, int out_size, void* d_ws, size_t ws_size,
                              hipStream_t stream) {
  (void)in_sizes; (void)n_in; (void)out_size; (void)ws_size;
  const float* x = (const float*)d_in[0];     // (B,T,C,H,W)
  const float* wgt = (const float*)d_in[1];   // (C,C,3,3)
  const float* bias = (const float*)d_in[2];  // (C,)
  float* out = (float*)d_out;                 // (B,T,C,H,W)

  float* ws = (float*)d_ws;
  float* f = ws;                    // NSTATE
  float* e = f + NSTATE;            // NSTATE
  float* lpl = e + NSTATE;          // BHW (l is channel-uniform)
  float* sA = lpl + BHW;            // BHW
  float* sB = sA + BHW;             // BHW
  float* wtr = sB + BHW;            // 9216

  k_wtr<<<36, 256, 0, stream>>>(wgt, wtr);
  k_step0<<<1024, 256, 0, stream>>>(x, bias, f, e, lpl, out, sA);

  float* s_in = sA;
  float* s_out = sB;
  for (int t = 1; t < T; ++t) {
    k_step<<<1024, 256, 0, stream>>>(x, wtr, bias, s_in, s_out, f, e, lpl, out, t);
    float* tmp = s_in; s_in = s_out; s_out = tmp;
  }
}

// Round 19
// 560.082 us; speedup vs baseline: 8.3337x; 1.0193x over previous
//
#include <hip/hip_runtime.h>
#include <math.h>

namespace {

constexpr int B = 8, T = 10, C = 32, H = 128, W = 128;
constexpr int HW = H * W;            // 16384
constexpr int CHW = C * HW;          // 524288
constexpr int BHW = B * HW;
constexpr long long NSTATE = (long long)B * CHW;

constexpr float DF = 0.90483741803595952f;  // exp(-0.1)
constexpr float DL = 0.36787944117144233f;  // exp(-1.0)
constexpr float DE = 0.36787944117144233f;  // exp(-1.0)
constexpr float VE = 10.0f;
constexpr float E0 = 3.6787944117144233f;   // DE * (V_E/ALPHA_E), e-fold init

typedef float floatx4 __attribute__((ext_vector_type(4)));  // NT-load-compatible

__device__ inline float4 nt_load4(const float* p) {
  floatx4 v = __builtin_nontemporal_load((const floatx4*)p);
  return make_float4(v.x, v.y, v.z, v.w);
}

// wgt[co][ci][kh][kw] -> wtr[ci][k][co]   (9216 floats)
__global__ void k_wtr(const float* __restrict__ wgt, float* __restrict__ wtr) {
  int i = blockIdx.x * 256 + threadIdx.x;
  if (i >= C * C * 9) return;
  int ci = i / 288;
  int k = (i / 32) % 9;
  int co = i & 31;
  wtr[i] = wgt[co * 288 + ci * 9 + k];
}

// t=0: y_prev=0 -> conv=0, l=0, u=f. Writes f, e_used(1), out[0], s, l-plane.
__launch_bounds__(256, 2)
__global__ void k_step0(const float* __restrict__ x, const float* __restrict__ bias,
                        float* __restrict__ f, float* __restrict__ e,
                        float* __restrict__ lpl, float* __restrict__ out,
                        float* __restrict__ s_out) {
  __shared__ float sred[8][32][4];
  const int tid = threadIdx.x, bid = blockIdx.x;
  const int wg = (bid & 7) * 128 + (bid >> 3);  // XCD swizzle: batch per XCD
  const int tw = wg & 7, th = (wg >> 3) & 15, b = wg >> 7;
  const int h0 = th * 8, w0 = tw * 16;
  const int g = tid >> 5, s = tid & 31;
  const int sh = s >> 2, sw = s & 3, cb = 4 * sw;
  const int gh = h0 + sh, gwc = w0 + cb;
  const float4 bc4 = *(const float4*)&bias[4 * g];
  const float bc[4] = {bc4.x, bc4.y, bc4.z, bc4.w};

  float sp[4] = {0.f, 0.f, 0.f, 0.f};
#pragma unroll
  for (int q = 0; q < 4; ++q) {
    const int c = 4 * g + q;
    const size_t sidx = (size_t)b * CHW + (size_t)c * HW + (size_t)gh * W + gwc;
    const size_t oidx = (((size_t)b * T) * C + c) * (size_t)HW + (size_t)gh * W + gwc;
    float4 x4 = nt_load4(x + oidx);
    float xr[4] = {x4.x, x4.y, x4.z, x4.w};
    float fo[4], eo[4], yn[4];
#pragma unroll
    for (int p = 0; p < 4; ++p) {
      float fn = bc[q] + xr[p];                  // DF*0 + conv(0) + bias + x
      float yy = 1.f / (1.f + __expf(E0 - fn));  // u = fn (l=0)
      fo[p] = fn;
      eo[p] = DE * E0 + VE * yy;                 // e_used(1)
      yn[p] = yy;
      sp[p] += yy;
    }
    *(float4*)(f + sidx) = make_float4(fo[0], fo[1], fo[2], fo[3]);
    *(float4*)(e + sidx) = make_float4(eo[0], eo[1], eo[2], eo[3]);
    *(float4*)(out + oidx) = make_float4(yn[0], yn[1], yn[2], yn[3]);
  }
  *(float4*)&sred[g][s][0] = make_float4(sp[0], sp[1], sp[2], sp[3]);
  __syncthreads();
  if (tid < 32) {
    float4 a = *(const float4*)&sred[0][tid][0];
#pragma unroll
    for (int gg = 1; gg < 8; ++gg) {
      float4 bq = *(const float4*)&sred[gg][tid][0];
      a.x += bq.x; a.y += bq.y; a.z += bq.z; a.w += bq.w;
    }
    const size_t pidx = (size_t)b * HW + (size_t)gh * W + gwc;
    *(float4*)(s_out + pidx) = a;
    *(float4*)(lpl + pidx) = make_float4(0.f, 0.f, 0.f, 0.f);  // l_1 = 0
  }
}

// Steps 1..T-1. R12 structure (verified 2x: ~58us/step, no spill) + two
// register-neutral levers:
//  (a) s_setprio(1) around the conv FMA cluster (T5): 4 blocks/CU sit at
//      different phases, so conv-phase waves win issue slots vs staging waves.
//  (b) non-temporal x loads: x is single-use; keep L2 for f/e/y (want-cached
//      set ~8MB/XCD vs 4MB L2 -- evicting x's 2MB stream raises hit rates).
__launch_bounds__(256, 2)
__global__ void k_step(const float* __restrict__ x, const float* __restrict__ wtr,
                       const float* __restrict__ bias, const float* __restrict__ s_in,
                       float* __restrict__ s_out, float* __restrict__ f,
                       float* __restrict__ e, float* __restrict__ lpl,
                       float* __restrict__ out, int t) {
  __shared__ float ysl[8][10][28];   // stride 28: rows 16B-aligned, 2-way banks
  __shared__ float wsl[8][9][32];    // [ci][k][c_out]
  __shared__ float sl[10][21];       // channel-sum tile (+halo)
  __shared__ float sred[8][32][4];   // chansum partials

  const int tid = threadIdx.x, bid = blockIdx.x;
  const int wg = (bid & 7) * 128 + (bid >> 3);  // XCD swizzle: batch per XCD
  const int tw = wg & 7, th = (wg >> 3) & 15, b = wg >> 7;
  const int h0 = th * 8, w0 = tw * 16;
  const int g = tid >> 5, s = tid & 31;
  const int sh = s >> 2, sw = s & 3, cb = 4 * sw;
  const int gh = h0 + sh, gwc = w0 + cb;

  const float* ybase = out + ((size_t)b * T + (t - 1)) * CHW;

  // stage channel-sum tile (visible after first barrier)
  for (int i = tid; i < 180; i += 256) {
    int rr = i / 18, cl = i % 18;
    int gh2 = h0 - 1 + rr, gw2 = w0 - 1 + cl;
    float v = 0.f;
    if ((unsigned)gh2 < (unsigned)H && (unsigned)gw2 < (unsigned)W)
      v = s_in[(size_t)b * HW + gh2 * W + gw2];
    sl[rr][cl] = v;
  }

  // l-plane read (channel-uniform); becomes l_new once linc is known
  float4 l4 = *(const float4*)(lpl + (size_t)b * HW + (size_t)gh * W + gwc);
  float lnew[4] = {l4.x, l4.y, l4.z, l4.w};

  // y-prefetch slots (chunk-invariant address parts). 480 float4 per chunk.
  const int i0 = tid;                                  // slot 0: always valid
  const int cil0 = i0 / 60, rr0 = (i0 % 60) / 6, j0 = i0 % 6;
  const int gh0p = h0 - 1 + rr0, ws0p = w0 - 4 + 4 * j0;
  const bool ok0 = (unsigned)gh0p < (unsigned)H && (unsigned)ws0p <= (unsigned)(W - 4);
  const size_t yoff0 = (size_t)cil0 * HW + (size_t)(ok0 ? gh0p * W + ws0p : 0);
  float* const yd0 = &ysl[cil0][rr0][4 * j0];
  const int i1 = tid + 256;                            // slot 1: valid if <480
  const bool use1 = i1 < 480;
  const int cil1 = (i1 / 60) & 7, rr1 = (i1 % 60) / 6, j1 = i1 % 6;
  const int gh1p = h0 - 1 + rr1, ws1p = w0 - 4 + 4 * j1;
  const bool ok1 = use1 && (unsigned)gh1p < (unsigned)H &&
                   (unsigned)ws1p <= (unsigned)(W - 4);
  const size_t yoff1 = (size_t)cil1 * HW + (size_t)(ok1 ? gh1p * W + ws1p : 0);
  float* const yd1 = &ysl[cil1][rr1][4 * j1];

  const float4* const wsrc = (const float4*)wtr;       // 576 float4 per chunk
  float4* const wlds = (float4*)&wsl[0][0][0];

  float4 y0v, y1v, w0v, w1v, w2v;
  auto prefetch = [&](int cc) {
    const float* yb = ybase + (size_t)cc * 8 * HW;
    y0v = ok0 ? *(const float4*)(yb + yoff0) : make_float4(0.f, 0.f, 0.f, 0.f);
    y1v = ok1 ? *(const float4*)(yb + yoff1) : make_float4(0.f, 0.f, 0.f, 0.f);
    const float4* wb = wsrc + cc * 576;
    w0v = wb[tid];
    w1v = wb[tid + 256];
    w2v = (tid < 64) ? wb[tid + 512] : make_float4(0.f, 0.f, 0.f, 0.f);
  };
  auto commit = [&]() {
    yd0[0] = y0v.x; yd0[1] = y0v.y; yd0[2] = y0v.z; yd0[3] = y0v.w;
    if (use1) { yd1[0] = y1v.x; yd1[1] = y1v.y; yd1[2] = y1v.z; yd1[3] = y1v.w; }
    wlds[tid] = w0v;
    wlds[tid + 256] = w1v;
    if (tid < 64) wlds[tid + 512] = w2v;
  };
  prefetch(0);

  float acc[4][4] = {};

  auto conv_chunk = [&]() {
    __builtin_amdgcn_s_setprio(1);   // favor conv-phase waves (T5)
#pragma unroll
    for (int cil = 0; cil < 8; ++cil) {
#pragma unroll
      for (int kh = 0; kh < 3; ++kh) {
        const float* rowp = &ysl[cil][sh + kh][0];
        float2 a2 = *(const float2*)(rowp + cb + 2);   // slots cb+2,cb+3
        float4 m4 = *(const float4*)(rowp + cb + 4);   // slots cb+4..cb+7
        float2 z2 = *(const float2*)(rowp + cb + 8);   // slots cb+8,cb+9
        const float yrow[6] = {a2.y, m4.x, m4.y, m4.z, m4.w, z2.x};
#pragma unroll
        for (int kw = 0; kw < 3; ++kw) {
          float4 wk = *(const float4*)&wsl[cil][3 * kh + kw][4 * g];
          const float wq[4] = {wk.x, wk.y, wk.z, wk.w};
#pragma unroll
          for (int q = 0; q < 4; ++q)
#pragma unroll
            for (int p = 0; p < 4; ++p)
              acc[q][p] = fmaf(wq[q], yrow[p + kw], acc[q][p]);
        }
      }
    }
    __builtin_amdgcn_s_setprio(0);
  };

#pragma unroll 1
  for (int cc = 0; cc < 3; ++cc) {
    __syncthreads();  // previous chunk's LDS reads complete
    commit();
    __syncthreads();  // LDS visible
    prefetch(cc + 1);  // next chunk's loads fly under these FMAs
    if (cc == 0) {
      float linc[4];
#pragma unroll
      for (int p = 0; p < 4; ++p) {
        const int c0 = cb + p;
        linc[p] = 0.5f * (sl[sh][c0] + sl[sh][c0 + 2] + sl[sh + 2][c0] +
                          sl[sh + 2][c0 + 2]) +
                  sl[sh][c0 + 1] + sl[sh + 2][c0 + 1] + sl[sh + 1][c0] +
                  sl[sh + 1][c0 + 2];
      }
#pragma unroll
      for (int p = 0; p < 4; ++p) lnew[p] = DL * lnew[p] + linc[p];
    }
    conv_chunk();
  }

  // chunk 3 (peeled): commit, then EARLY f/e loads (prefetch regs just died),
  // then the last FMA block — load latency hides under 1152 FMAs.
  __syncthreads();
  commit();
  __syncthreads();
  float4 fq4[4], eq4[4];
#pragma unroll
  for (int q = 0; q < 4; ++q) {
    const size_t sidx =
        (size_t)b * CHW + (size_t)(4 * g + q) * HW + (size_t)gh * W + gwc;
    fq4[q] = *(const float4*)(f + sidx);
    eq4[q] = *(const float4*)(e + sidx);
  }
  conv_chunk();

  // epilogue: f/e update (e-fold), out write, chansum partials
  const float4 bc4 = *(const float4*)&bias[4 * g];
  const float bc[4] = {bc4.x, bc4.y, bc4.z, bc4.w};
  float sp[4] = {0.f, 0.f, 0.f, 0.f};
#pragma unroll
  for (int q = 0; q < 4; ++q) {
    const int c = 4 * g + q;
    const size_t sidx = (size_t)b * CHW + (size_t)c * HW + (size_t)gh * W + gwc;
    const size_t oidx = (((size_t)b * T + t) * C + c) * (size_t)HW + (size_t)gh * W + gwc;
    float4 x4 = nt_load4(x + oidx);
    float fr[4] = {fq4[q].x, fq4[q].y, fq4[q].z, fq4[q].w};
    float er[4] = {eq4[q].x, eq4[q].y, eq4[q].z, eq4[q].w};
    float xr[4] = {x4.x, x4.y, x4.z, x4.w};
    float fo[4], eo[4], yn[4];
#pragma unroll
    for (int p = 0; p < 4; ++p) {
      float fn = DF * fr[p] + acc[q][p] + bc[q] + xr[p];
      float u = fmaf(0.5f * fn, lnew[p], fn);
      float yy = 1.f / (1.f + __expf(er[p] - u));
      fo[p] = fn;
      eo[p] = DE * er[p] + VE * yy;  // e_used(t+1)
      yn[p] = yy;
      sp[p] += yy;
    }
    *(float4*)(f + sidx) = make_float4(fo[0], fo[1], fo[2], fo[3]);
    *(float4*)(e + sidx) = make_float4(eo[0], eo[1], eo[2], eo[3]);
    *(float4*)(out + oidx) = make_float4(yn[0], yn[1], yn[2], yn[3]);
  }
  *(float4*)&sred[g][s][0] = make_float4(sp[0], sp[1], sp[2], sp[3]);
  __syncthreads();
  if (tid < 32) {  // g==0 threads span the tile
    float4 a = *(const float4*)&sred[0][tid][0];
#pragma unroll
    for (int gg = 1; gg < 8; ++gg) {
      float4 bq = *(const float4*)&sred[gg][tid][0];
      a.x += bq.x; a.y += bq.y; a.z += bq.z; a.w += bq.w;
    }
    const size_t pidx = (size_t)b * HW + (size_t)gh * W + gwc;
    *(float4*)(s_out + pidx) = a;
    *(float4*)(lpl + pidx) = make_float4(lnew[0], lnew[1], lnew[2], lnew[3]);
  }
}

}  // namespace

extern "C" void kernel_launch(void* const* d_in, const int* in_sizes, int n_in,
                              void* d_out, int out_size, void* d_ws, size_t ws_size,
                              hipStream_t stream) {
  (void)in_sizes; (void)n_in; (void)out_size; (void)ws_size;
  const float* x = (const float*)d_in[0];     // (B,T,C,H,W)
  const float* wgt = (const float*)d_in[1];   // (C,C,3,3)
  const float* bias = (const float*)d_in[2];  // (C,)
  float* out = (float*)d_out;                 // (B,T,C,H,W)

  float* ws = (float*)d_ws;
  float* f = ws;                    // NSTATE
  float* e = f + NSTATE;            // NSTATE
  float* lpl = e + NSTATE;          // BHW (l is channel-uniform)
  float* sA = lpl + BHW;            // BHW
  float* sB = sA + BHW;             // BHW
  float* wtr = sB + BHW;            // 9216

  k_wtr<<<36, 256, 0, stream>>>(wgt, wtr);
  k_step0<<<1024, 256, 0, stream>>>(x, bias, f, e, lpl, out, sA);

  float* s_in = sA;
  float* s_out = sB;
  for (int t = 1; t < T; ++t) {
    k_step<<<1024, 256, 0, stream>>>(x, wtr, bias, s_in, s_out, f, e, lpl, out, t);
    float* tmp = s_in; s_in = s_out; s_out = tmp;
  }
}

// Round 20
// 534.297 us; speedup vs baseline: 8.7359x; 1.0483x over previous
//
#include <hip/hip_runtime.h>
#include <math.h>

namespace {

constexpr int B = 8, T = 10, C = 32, H = 128, W = 128;
constexpr int HW = H * W;            // 16384
constexpr int CHW = C * HW;          // 524288
constexpr int BHW = B * HW;
constexpr long long NSTATE = (long long)B * CHW;

constexpr float DF = 0.90483741803595952f;  // exp(-0.1)
constexpr float DL = 0.36787944117144233f;  // exp(-1.0)
constexpr float DE = 0.36787944117144233f;  // exp(-1.0)
constexpr float VE = 10.0f;
constexpr float E0 = 3.6787944117144233f;   // DE * (V_E/ALPHA_E), e-fold init

typedef float floatx4 __attribute__((ext_vector_type(4)));  // NT-load-compatible

__device__ inline float4 nt_load4(const float* p) {
  floatx4 v = __builtin_nontemporal_load((const floatx4*)p);
  return make_float4(v.x, v.y, v.z, v.w);
}

// wgt[co][ci][kh][kw] -> wtr[ci][k][co]   (9216 floats)
__global__ void k_wtr(const float* __restrict__ wgt, float* __restrict__ wtr) {
  int i = blockIdx.x * 256 + threadIdx.x;
  if (i >= C * C * 9) return;
  int ci = i / 288;
  int k = (i / 32) % 9;
  int co = i & 31;
  wtr[i] = wgt[co * 288 + ci * 9 + k];
}

// t=0: y_prev=0 -> conv=0, l=0, u=f. Writes f, e_used(1), out[0], s, l-plane.
__launch_bounds__(256, 2)
__global__ void k_step0(const float* __restrict__ x, const float* __restrict__ bias,
                        float* __restrict__ f, float* __restrict__ e,
                        float* __restrict__ lpl, float* __restrict__ out,
                        float* __restrict__ s_out) {
  __shared__ float sred[8][32][4];
  const int tid = threadIdx.x, bid = blockIdx.x;
  const int wg = (bid & 7) * 128 + (bid >> 3);  // XCD swizzle: batch per XCD
  const int tw = wg & 7, th = (wg >> 3) & 15, b = wg >> 7;
  const int h0 = th * 8, w0 = tw * 16;
  const int g = tid >> 5, s = tid & 31;
  const int sh = s >> 2, sw = s & 3, cb = 4 * sw;
  const int gh = h0 + sh, gwc = w0 + cb;
  const float4 bc4 = *(const float4*)&bias[4 * g];
  const float bc[4] = {bc4.x, bc4.y, bc4.z, bc4.w};

  float sp[4] = {0.f, 0.f, 0.f, 0.f};
#pragma unroll
  for (int q = 0; q < 4; ++q) {
    const int c = 4 * g + q;
    const size_t sidx = (size_t)b * CHW + (size_t)c * HW + (size_t)gh * W + gwc;
    const size_t oidx = (((size_t)b * T) * C + c) * (size_t)HW + (size_t)gh * W + gwc;
    float4 x4 = nt_load4(x + oidx);
    float xr[4] = {x4.x, x4.y, x4.z, x4.w};
    float fo[4], eo[4], yn[4];
#pragma unroll
    for (int p = 0; p < 4; ++p) {
      float fn = bc[q] + xr[p];                  // DF*0 + conv(0) + bias + x
      float yy = 1.f / (1.f + __expf(E0 - fn));  // u = fn (l=0)
      fo[p] = fn;
      eo[p] = DE * E0 + VE * yy;                 // e_used(1)
      yn[p] = yy;
      sp[p] += yy;
    }
    *(float4*)(f + sidx) = make_float4(fo[0], fo[1], fo[2], fo[3]);
    *(float4*)(e + sidx) = make_float4(eo[0], eo[1], eo[2], eo[3]);
    *(float4*)(out + oidx) = make_float4(yn[0], yn[1], yn[2], yn[3]);
  }
  *(float4*)&sred[g][s][0] = make_float4(sp[0], sp[1], sp[2], sp[3]);
  __syncthreads();
  if (tid < 32) {
    float4 a = *(const float4*)&sred[0][tid][0];
#pragma unroll
    for (int gg = 1; gg < 8; ++gg) {
      float4 bq = *(const float4*)&sred[gg][tid][0];
      a.x += bq.x; a.y += bq.y; a.z += bq.z; a.w += bq.w;
    }
    const size_t pidx = (size_t)b * HW + (size_t)gh * W + gwc;
    *(float4*)(s_out + pidx) = a;
    *(float4*)(lpl + pidx) = make_float4(0.f, 0.f, 0.f, 0.f);  // l_1 = 0
  }
}

// Steps 1..T-1. R19 structure (best verified: 560us) + LDS bank-conflict fix:
// ysl row stride 28 -> 30. With stride 28, conv y-read bank-group =
// 4*((sw-row) mod 8): 32 lanes fold to 8 groups = 4-way conflict (1.58x,
// m136) on all y-reads = the entire 6.5M/step SQ_LDS_BANK_CONFLICT. Stride 30
// gives (4w-2r) mod 32 -> 16 groups = 2-way (free). Rows now only 8B-aligned:
// commit uses 2x float2 stores, window read 4x float2 (register-neutral).
__launch_bounds__(256, 2)
__global__ void k_step(const float* __restrict__ x, const float* __restrict__ wtr,
                       const float* __restrict__ bias, const float* __restrict__ s_in,
                       float* __restrict__ s_out, float* __restrict__ f,
                       float* __restrict__ e, float* __restrict__ lpl,
                       float* __restrict__ out, int t) {
  __shared__ float ysl[8][10][30];   // stride 30: 2-way banks on conv reads
  __shared__ float wsl[8][9][32];    // [ci][k][c_out] (reads are wave-broadcast)
  __shared__ float sl[10][21];       // channel-sum tile (+halo)
  __shared__ float sred[8][32][4];   // chansum partials

  const int tid = threadIdx.x, bid = blockIdx.x;
  const int wg = (bid & 7) * 128 + (bid >> 3);  // XCD swizzle: batch per XCD
  const int tw = wg & 7, th = (wg >> 3) & 15, b = wg >> 7;
  const int h0 = th * 8, w0 = tw * 16;
  const int g = tid >> 5, s = tid & 31;
  const int sh = s >> 2, sw = s & 3, cb = 4 * sw;
  const int gh = h0 + sh, gwc = w0 + cb;

  const float* ybase = out + ((size_t)b * T + (t - 1)) * CHW;

  // stage channel-sum tile (visible after first barrier)
  for (int i = tid; i < 180; i += 256) {
    int rr = i / 18, cl = i % 18;
    int gh2 = h0 - 1 + rr, gw2 = w0 - 1 + cl;
    float v = 0.f;
    if ((unsigned)gh2 < (unsigned)H && (unsigned)gw2 < (unsigned)W)
      v = s_in[(size_t)b * HW + gh2 * W + gw2];
    sl[rr][cl] = v;
  }

  // l-plane read (channel-uniform); becomes l_new once linc is known
  float4 l4 = *(const float4*)(lpl + (size_t)b * HW + (size_t)gh * W + gwc);
  float lnew[4] = {l4.x, l4.y, l4.z, l4.w};

  // y-prefetch slots (chunk-invariant address parts). 480 float4 per chunk.
  const int i0 = tid;                                  // slot 0: always valid
  const int cil0 = i0 / 60, rr0 = (i0 % 60) / 6, j0 = i0 % 6;
  const int gh0p = h0 - 1 + rr0, ws0p = w0 - 4 + 4 * j0;
  const bool ok0 = (unsigned)gh0p < (unsigned)H && (unsigned)ws0p <= (unsigned)(W - 4);
  const size_t yoff0 = (size_t)cil0 * HW + (size_t)(ok0 ? gh0p * W + ws0p : 0);
  float* const yd0 = &ysl[cil0][rr0][4 * j0];
  const int i1 = tid + 256;                            // slot 1: valid if <480
  const bool use1 = i1 < 480;
  const int cil1 = (i1 / 60) & 7, rr1 = (i1 % 60) / 6, j1 = i1 % 6;
  const int gh1p = h0 - 1 + rr1, ws1p = w0 - 4 + 4 * j1;
  const bool ok1 = use1 && (unsigned)gh1p < (unsigned)H &&
                   (unsigned)ws1p <= (unsigned)(W - 4);
  const size_t yoff1 = (size_t)cil1 * HW + (size_t)(ok1 ? gh1p * W + ws1p : 0);
  float* const yd1 = &ysl[cil1][rr1][4 * j1];

  const float4* const wsrc = (const float4*)wtr;       // 576 float4 per chunk
  float4* const wlds = (float4*)&wsl[0][0][0];

  float4 y0v, y1v, w0v, w1v, w2v;
  auto prefetch = [&](int cc) {
    const float* yb = ybase + (size_t)cc * 8 * HW;
    y0v = ok0 ? *(const float4*)(yb + yoff0) : make_float4(0.f, 0.f, 0.f, 0.f);
    y1v = ok1 ? *(const float4*)(yb + yoff1) : make_float4(0.f, 0.f, 0.f, 0.f);
    const float4* wb = wsrc + cc * 576;
    w0v = wb[tid];
    w1v = wb[tid + 256];
    w2v = (tid < 64) ? wb[tid + 512] : make_float4(0.f, 0.f, 0.f, 0.f);
  };
  auto commit = [&]() {  // rows 8B-aligned (stride 30): 2x float2 stores
    *(float2*)(yd0) = make_float2(y0v.x, y0v.y);
    *(float2*)(yd0 + 2) = make_float2(y0v.z, y0v.w);
    if (use1) {
      *(float2*)(yd1) = make_float2(y1v.x, y1v.y);
      *(float2*)(yd1 + 2) = make_float2(y1v.z, y1v.w);
    }
    wlds[tid] = w0v;
    wlds[tid + 256] = w1v;
    if (tid < 64) wlds[tid + 512] = w2v;
  };
  prefetch(0);

  float acc[4][4] = {};

  auto conv_chunk = [&]() {
    __builtin_amdgcn_s_setprio(1);   // favor conv-phase waves (T5)
#pragma unroll
    for (int cil = 0; cil < 8; ++cil) {
#pragma unroll
      for (int kh = 0; kh < 3; ++kh) {
        const float* rowp = &ysl[cil][sh + kh][0];
        float2 r0 = *(const float2*)(rowp + cb + 2);   // slots cb+2,cb+3
        float2 r1 = *(const float2*)(rowp + cb + 4);   // slots cb+4,cb+5
        float2 r2 = *(const float2*)(rowp + cb + 6);   // slots cb+6,cb+7
        float2 r3 = *(const float2*)(rowp + cb + 8);   // slots cb+8,cb+9
        const float yrow[6] = {r0.y, r1.x, r1.y, r2.x, r2.y, r3.x};
#pragma unroll
        for (int kw = 0; kw < 3; ++kw) {
          float4 wk = *(const float4*)&wsl[cil][3 * kh + kw][4 * g];
          const float wq[4] = {wk.x, wk.y, wk.z, wk.w};
#pragma unroll
          for (int q = 0; q < 4; ++q)
#pragma unroll
            for (int p = 0; p < 4; ++p)
              acc[q][p] = fmaf(wq[q], yrow[p + kw], acc[q][p]);
        }
      }
    }
    __builtin_amdgcn_s_setprio(0);
  };

#pragma unroll 1
  for (int cc = 0; cc < 3; ++cc) {
    __syncthreads();  // previous chunk's LDS reads complete
    commit();
    __syncthreads();  // LDS visible
    prefetch(cc + 1);  // next chunk's loads fly under these FMAs
    if (cc == 0) {
      float linc[4];
#pragma unroll
      for (int p = 0; p < 4; ++p) {
        const int c0 = cb + p;
        linc[p] = 0.5f * (sl[sh][c0] + sl[sh][c0 + 2] + sl[sh + 2][c0] +
                          sl[sh + 2][c0 + 2]) +
                  sl[sh][c0 + 1] + sl[sh + 2][c0 + 1] + sl[sh + 1][c0] +
                  sl[sh + 1][c0 + 2];
      }
#pragma unroll
      for (int p = 0; p < 4; ++p) lnew[p] = DL * lnew[p] + linc[p];
    }
    conv_chunk();
  }

  // chunk 3 (peeled): commit, then EARLY f/e loads (prefetch regs just died),
  // then the last FMA block — load latency hides under 1152 FMAs.
  __syncthreads();
  commit();
  __syncthreads();
  float4 fq4[4], eq4[4];
#pragma unroll
  for (int q = 0; q < 4; ++q) {
    const size_t sidx =
        (size_t)b * CHW + (size_t)(4 * g + q) * HW + (size_t)gh * W + gwc;
    fq4[q] = *(const float4*)(f + sidx);
    eq4[q] = *(const float4*)(e + sidx);
  }
  conv_chunk();

  // epilogue: f/e update (e-fold), out write, chansum partials
  const float4 bc4 = *(const float4*)&bias[4 * g];
  const float bc[4] = {bc4.x, bc4.y, bc4.z, bc4.w};
  float sp[4] = {0.f, 0.f, 0.f, 0.f};
#pragma unroll
  for (int q = 0; q < 4; ++q) {
    const int c = 4 * g + q;
    const size_t sidx = (size_t)b * CHW + (size_t)c * HW + (size_t)gh * W + gwc;
    const size_t oidx = (((size_t)b * T + t) * C + c) * (size_t)HW + (size_t)gh * W + gwc;
    float4 x4 = nt_load4(x + oidx);
    float fr[4] = {fq4[q].x, fq4[q].y, fq4[q].z, fq4[q].w};
    float er[4] = {eq4[q].x, eq4[q].y, eq4[q].z, eq4[q].w};
    float xr[4] = {x4.x, x4.y, x4.z, x4.w};
    float fo[4], eo[4], yn[4];
#pragma unroll
    for (int p = 0; p < 4; ++p) {
      float fn = DF * fr[p] + acc[q][p] + bc[q] + xr[p];
      float u = fmaf(0.5f * fn, lnew[p], fn);
      float yy = 1.f / (1.f + __expf(er[p] - u));
      fo[p] = fn;
      eo[p] = DE * er[p] + VE * yy;  // e_used(t+1)
      yn[p] = yy;
      sp[p] += yy;
    }
    *(float4*)(f + sidx) = make_float4(fo[0], fo[1], fo[2], fo[3]);
    *(float4*)(e + sidx) = make_float4(eo[0], eo[1], eo[2], eo[3]);
    *(float4*)(out + oidx) = make_float4(yn[0], yn[1], yn[2], yn[3]);
  }
  *(float4*)&sred[g][s][0] = make_float4(sp[0], sp[1], sp[2], sp[3]);
  __syncthreads();
  if (tid < 32) {  // g==0 threads span the tile
    float4 a = *(const float4*)&sred[0][tid][0];
#pragma unroll
    for (int gg = 1; gg < 8; ++gg) {
      float4 bq = *(const float4*)&sred[gg][tid][0];
      a.x += bq.x; a.y += bq.y; a.z += bq.z; a.w += bq.w;
    }
    const size_t pidx = (size_t)b * HW + (size_t)gh * W + gwc;
    *(float4*)(s_out + pidx) = a;
    *(float4*)(lpl + pidx) = make_float4(lnew[0], lnew[1], lnew[2], lnew[3]);
  }
}

}  // namespace

extern "C" void kernel_launch(void* const* d_in, const int* in_sizes, int n_in,
                              void* d_out, int out_size, void* d_ws, size_t ws_size,
                              hipStream_t stream) {
  (void)in_sizes; (void)n_in; (void)out_size; (void)ws_size;
  const float* x = (const float*)d_in[0];     // (B,T,C,H,W)
  const float* wgt = (const float*)d_in[1];   // (C,C,3,3)
  const float* bias = (const float*)d_in[2];  // (C,)
  float* out = (float*)d_out;                 // (B,T,C,H,W)

  float* ws = (float*)d_ws;
  float* f = ws;                    // NSTATE
  float* e = f + NSTATE;            // NSTATE
  float* lpl = e + NSTATE;          // BHW (l is channel-uniform)
  float* sA = lpl + BHW;            // BHW
  float* sB = sA + BHW;             // BHW
  float* wtr = sB + BHW;            // 9216

  k_wtr<<<36, 256, 0, stream>>>(wgt, wtr);
  k_step0<<<1024, 256, 0, stream>>>(x, bias, f, e, lpl, out, sA);

  float* s_in = sA;
  float* s_out = sB;
  for (int t = 1; t < T; ++t) {
    k_step<<<1024, 256, 0, stream>>>(x, wtr, bias, s_in, s_out, f, e, lpl, out, t);
    float* tmp = s_in; s_in = s_out; s_out = tmp;
  }
}